// Round 17
// baseline (92.832 us; speedup 1.0000x reference)
//
#include <hip/hip_runtime.h>
#include <hip/hip_bf16.h>

typedef __bf16 bf16x8 __attribute__((ext_vector_type(8)));
typedef float f32x4 __attribute__((ext_vector_type(4)));

static __device__ __forceinline__ unsigned short f2bf(float x) {
    __hip_bfloat16 b = __float2bfloat16(x);
    return __builtin_bit_cast(unsigned short, b);
}
static __device__ __forceinline__ float bf2f(unsigned short u) {
    __hip_bfloat16 b = __builtin_bit_cast(__hip_bfloat16, u);
    return __bfloat162float(b);
}

static __device__ __forceinline__ void gload_lds16(const void* g, void* l) {
    __builtin_amdgcn_global_load_lds(
        (const __attribute__((address_space(1))) void*)g,
        (__attribute__((address_space(3))) void*)l, 16, 0, 0);
}

// ---- fused prep: weight transposes/splits (blocks 0..2239) + value->bf16 slice (rest) ----
__global__ __launch_bounds__(256) void prep_all(
    const float* __restrict__ w_value, const float* __restrict__ w_out,
    const float* __restrict__ w_off, const float* __restrict__ w_attw,
    const float* __restrict__ value,
    unsigned short* __restrict__ WvT, unsigned short* __restrict__ WoT,
    unsigned short* __restrict__ WThi, unsigned short* __restrict__ WTlo,
    unsigned short* __restrict__ Vbf) {
    const int bid = blockIdx.x;
    const int tid = threadIdx.x;
    if (bid >= 2240) {
        int g = (bid - 2240) * 256 + tid;
        int r4 = g >> 8;
        int cpos = g & 255;
        int b = r4 / 2176;
        int l = 1920 + (r4 % 2176);
        size_t off4 = (size_t)(b * 4096 + l) * 256 + cpos;
        float4 v = reinterpret_cast<const float4*>(value)[off4];
        ushort4 o;
        o.x = f2bf(v.x); o.y = f2bf(v.y); o.z = f2bf(v.z); o.w = f2bf(v.w);
        reinterpret_cast<ushort4*>(Vbf)[off4] = o;
        return;
    }
    __shared__ float tile[32][33];
    const int sel = bid >> 5;            // 0..69
    const int k0 = (bid & 31) * 32;
    const int tx = tid & 31, ty = tid >> 5;  // (32, 8)
    if (sel < 64) {
        const float* in = (sel < 32) ? w_value : w_out;
        unsigned short* out = (sel < 32) ? WvT : WoT;
        const int n0 = (sel & 31) * 32;
        for (int i = ty; i < 32; i += 8) tile[i][tx] = in[(size_t)(k0 + i) * 1024 + n0 + tx];
        __syncthreads();
        for (int i = ty; i < 32; i += 8)
            out[(size_t)(n0 + i) * 1024 + k0 + tx] = f2bf(tile[tx][i]);
    } else {
        const int n0 = (sel - 64) * 32;
        for (int i = ty; i < 32; i += 8) {
            int n = n0 + tx;
            tile[i][tx] = (n < 128) ? w_off[(size_t)(k0 + i) * 128 + n]
                                    : w_attw[(size_t)(k0 + i) * 64 + (n - 128)];
        }
        __syncthreads();
        for (int i = ty; i < 32; i += 8) {
            int n = n0 + i, k = k0 + tx;
            float v = tile[tx][i];
            unsigned short hi = f2bf(v);
            unsigned short lo = f2bf(v - bf2f(hi));
            WThi[(size_t)n * 1024 + k] = hi;
            WTlo[(size_t)n * 1024 + k] = lo;
        }
    }
}

// ---------------- off/attw logits via split-bf16 MFMA ----------------
// BM=64, BN=192, BK=64, split-K=4 (4 k-steps each). A reg-staged (rows padded to 72);
// B via gload_lds chunk-XOR swizzled. 72 MFMA/wave per k-step.
__global__ __launch_bounds__(256, 2) void offw_mfma(
    const float* __restrict__ query,          // 8192 x 1024 fp32
    const unsigned short* __restrict__ WThi,  // 192 x 1024 bf16
    const unsigned short* __restrict__ WTlo,
    float* __restrict__ part) {
    __shared__ unsigned short Ahi[64 * 72], Alo[64 * 72];   // 18 KB
    __shared__ unsigned short Bs2[2 * 192 * 64];            // 48 KB
    const int tid = threadIdx.x;
    const int lane = tid & 63, wave = tid >> 6;    // wave = col group 0..3
    const int bm = blockIdx.x * 64;
    const int sk = blockIdx.y;
    const int r = lane & 15, kq = lane >> 4;
    const int kx = kq ^ (r & 3);                   // swizzled chunk slot (low 2 bits)

    f32x4 acc[4][3];
    #pragma unroll
    for (int i = 0; i < 4; ++i)
        #pragma unroll
        for (int j = 0; j < 3; ++j) acc[i][j] = (f32x4){0.f, 0.f, 0.f, 0.f};

    const int arow = tid >> 2;           // 0..63
    const int apos = (tid & 3) * 16;     // 16 floats per thread

    for (int k0 = sk * 256; k0 < sk * 256 + 256; k0 += 64) {
        // --- stage A: 16 fp32 -> hi/lo bf16, ds_write (padded rows) ---
        const float* qp = query + (size_t)(bm + arow) * 1024 + k0 + apos;
        unsigned int hw[8], lw[8];
        #pragma unroll
        for (int t = 0; t < 4; ++t) {
            float4 qf = reinterpret_cast<const float4*>(qp)[t];
            unsigned short h0 = f2bf(qf.x), h1 = f2bf(qf.y), h2 = f2bf(qf.z), h3 = f2bf(qf.w);
            unsigned short l0 = f2bf(qf.x - bf2f(h0)), l1 = f2bf(qf.y - bf2f(h1));
            unsigned short l2 = f2bf(qf.z - bf2f(h2)), l3 = f2bf(qf.w - bf2f(h3));
            hw[t * 2] = (unsigned int)h0 | ((unsigned int)h1 << 16);
            hw[t * 2 + 1] = (unsigned int)h2 | ((unsigned int)h3 << 16);
            lw[t * 2] = (unsigned int)l0 | ((unsigned int)l1 << 16);
            lw[t * 2 + 1] = (unsigned int)l2 | ((unsigned int)l3 << 16);
        }
        *reinterpret_cast<uint4*>(&Ahi[arow * 72 + apos]) = (uint4){hw[0], hw[1], hw[2], hw[3]};
        *reinterpret_cast<uint4*>(&Ahi[arow * 72 + apos + 8]) = (uint4){hw[4], hw[5], hw[6], hw[7]};
        *reinterpret_cast<uint4*>(&Alo[arow * 72 + apos]) = (uint4){lw[0], lw[1], lw[2], lw[3]};
        *reinterpret_cast<uint4*>(&Alo[arow * 72 + apos + 8]) = (uint4){lw[4], lw[5], lw[6], lw[7]};
        // --- stage B: 2 planes x 192 rows x 8 chunks = 3072 chunks, 12/thread ---
        #pragma unroll
        for (int t = 0; t < 12; ++t) {
            int c = tid + 256 * t;                 // c&63 == lane
            int plane = (c >= 1536);
            int cp = c - 1536 * plane;
            int crow = cp >> 3;
            int ccol = ((cp & 3) ^ (crow & 3)) | (cp & 4);
            const unsigned short* src = (plane ? WTlo : WThi)
                + (size_t)crow * 1024 + k0 + ccol * 8;
            gload_lds16(src, &Bs2[(size_t)(c & ~63) * 8]);
        }
        __syncthreads();

        #pragma unroll
        for (int kh = 0; kh < 2; ++kh) {
            bf16x8 bh[3], bl[3];
            #pragma unroll
            for (int j = 0; j < 3; ++j) {
                int ro = (wave * 48 + j * 16 + r) * 64 + (kh * 4 + kx) * 8;
                bh[j] = *reinterpret_cast<const bf16x8*>(&Bs2[ro]);
                bl[j] = *reinterpret_cast<const bf16x8*>(&Bs2[192 * 64 + ro]);
            }
            #pragma unroll
            for (int i = 0; i < 4; ++i) {
                int ro = (i * 16 + r) * 72 + (kh * 4 + kq) * 8;
                bf16x8 ah = *reinterpret_cast<const bf16x8*>(&Ahi[ro]);
                bf16x8 al = *reinterpret_cast<const bf16x8*>(&Alo[ro]);
                #pragma unroll
                for (int j = 0; j < 3; ++j) {
                    acc[i][j] = __builtin_amdgcn_mfma_f32_16x16x32_bf16(ah, bh[j], acc[i][j], 0, 0, 0);
                    acc[i][j] = __builtin_amdgcn_mfma_f32_16x16x32_bf16(ah, bl[j], acc[i][j], 0, 0, 0);
                    acc[i][j] = __builtin_amdgcn_mfma_f32_16x16x32_bf16(al, bh[j], acc[i][j], 0, 0, 0);
                }
            }
        }
        __syncthreads();
    }

    float* P = part + (size_t)sk * 8192 * 192;
    #pragma unroll
    for (int i = 0; i < 4; ++i) {
        int row0 = bm + i * 16 + kq * 4;
        #pragma unroll
        for (int j = 0; j < 3; ++j) {
            int col = wave * 48 + j * 16 + r;
            #pragma unroll
            for (int rr = 0; rr < 4; ++rr)
                P[(size_t)(row0 + rr) * 192 + col] = acc[i][j][rr];
        }
    }
}

// ---- value projection GEMM: Vproj = Vbf @ WvT^T + b_value (bf16 out) ----
// BM=128, BN=64, BK=128 (48 KB LDS), 544 blocks XCD-chunked, chunk-XOR swizzle.
__global__ __launch_bounds__(256, 2) void vproj_mfma(
    const unsigned short* __restrict__ Vbf,
    const unsigned short* __restrict__ WvT,
    const float* __restrict__ bias,
    unsigned short* __restrict__ Vproj) {
    __shared__ unsigned short As[128 * 128];  // 32 KB
    __shared__ unsigned short Bs[64 * 128];   // 16 KB
    const int tid = threadIdx.x;
    const int lane = tid & 63, wave = tid >> 6;
    const int i0 = blockIdx.x;                     // 0..543
    const int s = (i0 & 7) * 68 + (i0 >> 3);       // bijective (544 = 8*68)
    const int pa = s >> 4;
    const int by = s & 15;
    const int bz = (pa >= 17) ? 1 : 0;
    const int bx = pa - 17 * bz;
    const int bm = 1920 + bz * 4096 + bx * 128;
    const int bn = by * 64;
    const int r = lane & 15, kq = lane >> 4;
    const int kx = kq ^ (r & 3);

    f32x4 acc[2][4];
    #pragma unroll
    for (int i = 0; i < 2; ++i)
        #pragma unroll
        for (int j = 0; j < 4; ++j) acc[i][j] = (f32x4){0.f, 0.f, 0.f, 0.f};

    for (int k0 = 0; k0 < 1024; k0 += 128) {
        #pragma unroll
        for (int t = 0; t < 8; ++t) {   // A: 128 rows x 16 chunks = 2048 chunks
            int c = tid + 256 * t;
            int crow = c >> 4;
            int cc = c & 15;
            int ccol = ((cc & 3) ^ (crow & 3)) | (cc & 12);
            gload_lds16(Vbf + (size_t)(bm + crow) * 1024 + k0 + ccol * 8,
                        &As[(size_t)(c & ~63) * 8]);
        }
        #pragma unroll
        for (int t = 0; t < 4; ++t) {   // B: 64 rows x 16 chunks = 1024 chunks
            int c = tid + 256 * t;
            int crow = c >> 4;
            int cc = c & 15;
            int ccol = ((cc & 3) ^ (crow & 3)) | (cc & 12);
            gload_lds16(WvT + (size_t)(bn + crow) * 1024 + k0 + ccol * 8,
                        &Bs[(size_t)(c & ~63) * 8]);
        }
        __syncthreads();

        #pragma unroll
        for (int kh = 0; kh < 4; ++kh) {
            bf16x8 af[2], bfr[4];
            #pragma unroll
            for (int i = 0; i < 2; ++i)
                af[i] = *reinterpret_cast<const bf16x8*>(
                    &As[(wave * 32 + i * 16 + r) * 128 + (kh * 4 + kx) * 8]);
            #pragma unroll
            for (int j = 0; j < 4; ++j)
                bfr[j] = *reinterpret_cast<const bf16x8*>(
                    &Bs[(j * 16 + r) * 128 + (kh * 4 + kx) * 8]);
            #pragma unroll
            for (int i = 0; i < 2; ++i)
                #pragma unroll
                for (int j = 0; j < 4; ++j)
                    acc[i][j] = __builtin_amdgcn_mfma_f32_16x16x32_bf16(af[i], bfr[j], acc[i][j], 0, 0, 0);
        }
        __syncthreads();
    }

    #pragma unroll
    for (int i = 0; i < 2; ++i) {
        int row0 = bm + wave * 32 + i * 16 + kq * 4;
        #pragma unroll
        for (int j = 0; j < 4; ++j) {
            int col = bn + j * 16 + r;
            float bs = bias[col];
            #pragma unroll
            for (int rr = 0; rr < 4; ++rr)
                Vproj[(size_t)(row0 + rr) * 1024 + col] = f2bf(acc[i][j][rr] + bs);
        }
    }
}

// ------- fused: partial-sum + bias + softmax + coefficients + gather (2 rows/block) -------
__global__ __launch_bounds__(256) void sample_coef(
    const float* __restrict__ part, const float* __restrict__ b_off,
    const float* __restrict__ b_attw, const unsigned short* __restrict__ vproj,
    unsigned short* __restrict__ s_out) {
    const int n0 = blockIdx.x * 2;   // rows n0, n0+1 (same batch)
    const int tid = threadIdx.x;
    __shared__ float Ls[2][192];
    __shared__ int sIdx[2][64];
    __shared__ float sC0[2][64], sC1[2][64];
    const size_t SK = (size_t)8192 * 192;
    for (int e = tid; e < 384; e += 256) {
        int ri = (e >= 192);
        int c = e - ri * 192;
        const float* Pn = part + (size_t)(n0 + ri) * 192 + c;
        float s = (c < 128) ? b_off[c] : b_attw[c - 128];
        Ls[ri][c] = s + Pn[0] + Pn[SK] + Pn[2 * SK] + Pn[3 * SK];
    }
    __syncthreads();
    if (tid < 128) {
        int ri = tid >> 6, e = tid & 63;
        int l = (n0 + ri) & 4095;
        int h = e >> 2, p = e & 3;
        float l0 = Ls[ri][128 + h * 4 + 0], l1 = Ls[ri][128 + h * 4 + 1];
        float l2 = Ls[ri][128 + h * 4 + 2], l3 = Ls[ri][128 + h * 4 + 3];
        float mx = fmaxf(fmaxf(l0, l1), fmaxf(l2, l3));
        float e0 = expf(l0 - mx), e1 = expf(l1 - mx), e2 = expf(l2 - mx), e3 = expf(l3 - mx);
        float esum = e0 + e1 + e2 + e3;
        float aw = ((p == 0) ? e0 : (p == 1) ? e1 : (p == 2) ? e2 : e3) / esum;
        float o0 = Ls[ri][h * 8 + p * 2], o1 = Ls[ri][h * 8 + p * 2 + 1];
        float sx = fminf(fmaxf(o0, 0.f), 1.f);
        float ry = (float)l / 4095.0f;
        float sy = fminf(fmaxf(ry + o1, 0.f), 1.f);
        float ix = ((sx + 1.f) * 4096.f - 1.f) * 0.5f;
        float iy = sy * 0.5f;
        float x0f = floorf(ix);
        float fx = ix - x0f;
        int x0 = (int)x0f;
        int x1 = x0 + 1;
        float m0 = (x0 >= 0 && x0 < 4096) ? 1.f : 0.f;
        float m1 = (x1 >= 0 && x1 < 4096) ? 1.f : 0.f;
        float y0f = floorf(iy);
        float fy = iy - y0f;
        float hy = ((y0f == 0.f) ? (1.f - fy) : 0.f) + ((y0f == -1.f) ? fy : 0.f);
        sC0[ri][e] = aw * (1.f - fx) * m0 * hy;
        sC1[ri][e] = aw * fx * m1 * hy;
        sIdx[ri][e] = x0 < 0 ? 0 : (x0 > 4095 ? 4095 : x0);
    }
    __syncthreads();
    const int d = tid * 4;
    const int h = tid >> 4;
    const size_t vb = (size_t)(n0 >> 12) * 4096 * 1024;
    #pragma unroll
    for (int ri = 0; ri < 2; ++ri) {
        float a0 = 0.f, a1 = 0.f, a2 = 0.f, a3 = 0.f;
        #pragma unroll
        for (int p = 0; p < 4; ++p) {
            int e = h * 4 + p;
            int x0 = sIdx[ri][e];
            float c0 = sC0[ri][e], c1 = sC1[ri][e];
            int x1 = (x0 + 1 > 4095) ? 4095 : x0 + 1;
            ushort4 v0 = *reinterpret_cast<const ushort4*>(vproj + vb + (size_t)x0 * 1024 + d);
            ushort4 v1 = *reinterpret_cast<const ushort4*>(vproj + vb + (size_t)x1 * 1024 + d);
            a0 += c0 * bf2f(v0.x) + c1 * bf2f(v1.x);
            a1 += c0 * bf2f(v0.y) + c1 * bf2f(v1.y);
            a2 += c0 * bf2f(v0.z) + c1 * bf2f(v1.z);
            a3 += c0 * bf2f(v0.w) + c1 * bf2f(v1.w);
        }
        ushort4 o;
        o.x = f2bf(a0); o.y = f2bf(a1); o.z = f2bf(a2); o.w = f2bf(a3);
        *reinterpret_cast<ushort4*>(s_out + (size_t)(n0 + ri) * 1024 + d) = o;
    }
}

// ---- final GEMM: out = S @ WoT^T + b_out (fp32). BK=128 (64 KB LDS), XCD-chunked. ----
__global__ __launch_bounds__(256, 2) void gemm_bt(
    const unsigned short* __restrict__ A,   // S 8192 x 1024 bf16
    const unsigned short* __restrict__ Bt,  // WoT 1024 x 1024 bf16
    const float* __restrict__ bias,         // b_out
    float* __restrict__ C) {
    __shared__ unsigned short As[128 * 128];  // 32 KB
    __shared__ unsigned short Bs[128 * 128];  // 32 KB
    const int tid = threadIdx.x;
    const int lane = tid & 63;
    const int wave = tid >> 6;
    const int i0 = blockIdx.x;                // 0..511
    const int s = (i0 & 7) * 64 + (i0 >> 3);  // bijective (512 = 8*64)
    const int bm = (s >> 3) * 128;
    const int bn = (s & 7) * 128;
    const int wr = wave >> 1;
    const int wc = wave & 1;
    const int r = lane & 15;
    const int kq = lane >> 4;
    const int kx = kq ^ (r & 3);

    f32x4 acc[4][4];
    #pragma unroll
    for (int i = 0; i < 4; ++i)
        #pragma unroll
        for (int j = 0; j < 4; ++j) acc[i][j] = (f32x4){0.f, 0.f, 0.f, 0.f};

    for (int k0 = 0; k0 < 1024; k0 += 128) {
        const unsigned short* Ab = A + (size_t)bm * 1024 + k0;
        const unsigned short* Bb = Bt + (size_t)bn * 1024 + k0;
        #pragma unroll
        for (int t = 0; t < 8; ++t) {   // 2048 chunks per operand, 8/thread
            int c = tid + 256 * t;
            int crow = c >> 4;
            int cc = c & 15;
            int ccol = ((cc & 3) ^ (crow & 3)) | (cc & 12);
            gload_lds16(Ab + (size_t)crow * 1024 + ccol * 8, &As[(size_t)(c & ~63) * 8]);
        }
        #pragma unroll
        for (int t = 0; t < 8; ++t) {
            int c = tid + 256 * t;
            int crow = c >> 4;
            int cc = c & 15;
            int ccol = ((cc & 3) ^ (crow & 3)) | (cc & 12);
            gload_lds16(Bb + (size_t)crow * 1024 + ccol * 8, &Bs[(size_t)(c & ~63) * 8]);
        }
        __syncthreads();

        #pragma unroll
        for (int kh = 0; kh < 4; ++kh) {
            bf16x8 af[4], bfr[4];
            #pragma unroll
            for (int i = 0; i < 4; ++i)
                af[i] = *reinterpret_cast<const bf16x8*>(
                    &As[(wr * 64 + i * 16 + r) * 128 + (kh * 4 + kx) * 8]);
            #pragma unroll
            for (int j = 0; j < 4; ++j)
                bfr[j] = *reinterpret_cast<const bf16x8*>(
                    &Bs[(wc * 64 + j * 16 + r) * 128 + (kh * 4 + kx) * 8]);
            #pragma unroll
            for (int i = 0; i < 4; ++i)
                #pragma unroll
                for (int j = 0; j < 4; ++j)
                    acc[i][j] = __builtin_amdgcn_mfma_f32_16x16x32_bf16(af[i], bfr[j], acc[i][j], 0, 0, 0);
        }
        __syncthreads();
    }

    #pragma unroll
    for (int i = 0; i < 4; ++i) {
        int row0 = bm + wr * 64 + i * 16 + kq * 4;
        #pragma unroll
        for (int j = 0; j < 4; ++j) {
            int col = bn + wc * 64 + j * 16 + r;
            float bs = bias[col];
            #pragma unroll
            for (int rr = 0; rr < 4; ++rr)
                C[(size_t)(row0 + rr) * 1024 + col] = acc[i][j][rr] + bs;
        }
    }
}

extern "C" void kernel_launch(void* const* d_in, const int* in_sizes, int n_in,
                              void* d_out, int out_size, void* d_ws, size_t ws_size,
                              hipStream_t stream) {
    const float* query  = (const float*)d_in[0];
    const float* value  = (const float*)d_in[2];
    const float* w_value = (const float*)d_in[5];
    const float* b_value = (const float*)d_in[6];
    const float* w_off   = (const float*)d_in[7];
    const float* b_off   = (const float*)d_in[8];
    const float* w_attw  = (const float*)d_in[9];
    const float* b_attw  = (const float*)d_in[10];
    const float* w_out   = (const float*)d_in[11];
    const float* b_out   = (const float*)d_in[12];
    float* out = (float*)d_out;

    char* w = (char*)d_ws;
    unsigned short* Vbf   = (unsigned short*)(w);                       // 0..16
    unsigned short* WvT   = (unsigned short*)(w + (16ull << 20));       // 16..18
    unsigned short* WoT   = (unsigned short*)(w + (18ull << 20));       // 18..20
    unsigned short* Vproj = (unsigned short*)(w + (20ull << 20));       // 20..36
    unsigned short* S     = (unsigned short*)(w + (36ull << 20));       // 36..52
    unsigned short* WThi  = (unsigned short*)(w + (53ull << 20));       // 53..53.4
    unsigned short* WTlo  = (unsigned short*)(w + (54ull << 20));       // 54..54.4
    float*          Part  = (float*)(w + (56ull << 20));                // 56..81.2
    // all regions disjoint; no lifetime aliasing.

    // 1. fused prep: weight transposes/splits + value->bf16 slice
    prep_all<<<6592, 256, 0, stream>>>(w_value, w_out, w_off, w_attw, value,
                                       WvT, WoT, WThi, WTlo, Vbf);
    // 2. off/attw logits via split-bf16 MFMA (split-K=4 partials), BK=64
    offw_mfma<<<dim3(128, 4), 256, 0, stream>>>(query, WThi, WTlo, Part);
    // 3. v = Vbf @ w_value + b_value (bf16 out), BK=128, XCD-swz
    vproj_mfma<<<544, 256, 0, stream>>>(Vbf, WvT, b_value, Vproj);
    // 4. partial-sum + bias + softmax + coefficients + gather -> s (bf16), 2 rows/block
    sample_coef<<<4096, 256, 0, stream>>>(Part, b_off, b_attw, Vproj, S);
    // 5. out = s @ w_out + b_out (fp32 out), BK=128, XCD-swz
    gemm_bt<<<512, 256, 0, stream>>>(S, WoT, b_out, out);
}

// Round 18
// 86.252 us; speedup vs baseline: 1.0763x; 1.0763x over previous
//
#include <hip/hip_runtime.h>
#include <hip/hip_bf16.h>

typedef __bf16 bf16x8 __attribute__((ext_vector_type(8)));
typedef float f32x4 __attribute__((ext_vector_type(4)));

static __device__ __forceinline__ unsigned short f2bf(float x) {
    __hip_bfloat16 b = __float2bfloat16(x);
    return __builtin_bit_cast(unsigned short, b);
}
static __device__ __forceinline__ float bf2f(unsigned short u) {
    __hip_bfloat16 b = __builtin_bit_cast(__hip_bfloat16, u);
    return __bfloat162float(b);
}

static __device__ __forceinline__ void gload_lds16(const void* g, void* l) {
    __builtin_amdgcn_global_load_lds(
        (const __attribute__((address_space(1))) void*)g,
        (__attribute__((address_space(3))) void*)l, 16, 0, 0);
}

// ---- fused prep: weight transposes/splits (blocks 0..2239) + value->bf16 slice (rest) ----
__global__ __launch_bounds__(256) void prep_all(
    const float* __restrict__ w_value, const float* __restrict__ w_out,
    const float* __restrict__ w_off, const float* __restrict__ w_attw,
    const float* __restrict__ value,
    unsigned short* __restrict__ WvT, unsigned short* __restrict__ WoT,
    unsigned short* __restrict__ WThi, unsigned short* __restrict__ WTlo,
    unsigned short* __restrict__ Vbf) {
    const int bid = blockIdx.x;
    const int tid = threadIdx.x;
    if (bid >= 2240) {
        int g = (bid - 2240) * 256 + tid;
        int r4 = g >> 8;
        int cpos = g & 255;
        int b = r4 / 2176;
        int l = 1920 + (r4 % 2176);
        size_t off4 = (size_t)(b * 4096 + l) * 256 + cpos;
        float4 v = reinterpret_cast<const float4*>(value)[off4];
        ushort4 o;
        o.x = f2bf(v.x); o.y = f2bf(v.y); o.z = f2bf(v.z); o.w = f2bf(v.w);
        reinterpret_cast<ushort4*>(Vbf)[off4] = o;
        return;
    }
    __shared__ float tile[32][33];
    const int sel = bid >> 5;            // 0..69
    const int k0 = (bid & 31) * 32;
    const int tx = tid & 31, ty = tid >> 5;  // (32, 8)
    if (sel < 64) {
        const float* in = (sel < 32) ? w_value : w_out;
        unsigned short* out = (sel < 32) ? WvT : WoT;
        const int n0 = (sel & 31) * 32;
        for (int i = ty; i < 32; i += 8) tile[i][tx] = in[(size_t)(k0 + i) * 1024 + n0 + tx];
        __syncthreads();
        for (int i = ty; i < 32; i += 8)
            out[(size_t)(n0 + i) * 1024 + k0 + tx] = f2bf(tile[tx][i]);
    } else {
        const int n0 = (sel - 64) * 32;
        for (int i = ty; i < 32; i += 8) {
            int n = n0 + tx;
            tile[i][tx] = (n < 128) ? w_off[(size_t)(k0 + i) * 128 + n]
                                    : w_attw[(size_t)(k0 + i) * 64 + (n - 128)];
        }
        __syncthreads();
        for (int i = ty; i < 32; i += 8) {
            int n = n0 + i, k = k0 + tx;
            float v = tile[tx][i];
            unsigned short hi = f2bf(v);
            unsigned short lo = f2bf(v - bf2f(hi));
            WThi[(size_t)n * 1024 + k] = hi;
            WTlo[(size_t)n * 1024 + k] = lo;
        }
    }
}

// ---------------- off/attw logits via split-bf16 MFMA ----------------
// BM=64, BN=192, BK=64, split-K=4 (4 k-steps each). A reg-staged (rows padded to 72);
// B via gload_lds chunk-XOR swizzled. 72 MFMA/wave per k-step.
__global__ __launch_bounds__(256, 2) void offw_mfma(
    const float* __restrict__ query,          // 8192 x 1024 fp32
    const unsigned short* __restrict__ WThi,  // 192 x 1024 bf16
    const unsigned short* __restrict__ WTlo,
    float* __restrict__ part) {
    __shared__ unsigned short Ahi[64 * 72], Alo[64 * 72];   // 18 KB
    __shared__ unsigned short Bs2[2 * 192 * 64];            // 48 KB
    const int tid = threadIdx.x;
    const int lane = tid & 63, wave = tid >> 6;    // wave = col group 0..3
    const int bm = blockIdx.x * 64;
    const int sk = blockIdx.y;
    const int r = lane & 15, kq = lane >> 4;
    const int kx = kq ^ (r & 3);                   // swizzled chunk slot (low 2 bits)

    f32x4 acc[4][3];
    #pragma unroll
    for (int i = 0; i < 4; ++i)
        #pragma unroll
        for (int j = 0; j < 3; ++j) acc[i][j] = (f32x4){0.f, 0.f, 0.f, 0.f};

    const int arow = tid >> 2;           // 0..63
    const int apos = (tid & 3) * 16;     // 16 floats per thread

    for (int k0 = sk * 256; k0 < sk * 256 + 256; k0 += 64) {
        // --- stage A: 16 fp32 -> hi/lo bf16, ds_write (padded rows) ---
        const float* qp = query + (size_t)(bm + arow) * 1024 + k0 + apos;
        unsigned int hw[8], lw[8];
        #pragma unroll
        for (int t = 0; t < 4; ++t) {
            float4 qf = reinterpret_cast<const float4*>(qp)[t];
            unsigned short h0 = f2bf(qf.x), h1 = f2bf(qf.y), h2 = f2bf(qf.z), h3 = f2bf(qf.w);
            unsigned short l0 = f2bf(qf.x - bf2f(h0)), l1 = f2bf(qf.y - bf2f(h1));
            unsigned short l2 = f2bf(qf.z - bf2f(h2)), l3 = f2bf(qf.w - bf2f(h3));
            hw[t * 2] = (unsigned int)h0 | ((unsigned int)h1 << 16);
            hw[t * 2 + 1] = (unsigned int)h2 | ((unsigned int)h3 << 16);
            lw[t * 2] = (unsigned int)l0 | ((unsigned int)l1 << 16);
            lw[t * 2 + 1] = (unsigned int)l2 | ((unsigned int)l3 << 16);
        }
        *reinterpret_cast<uint4*>(&Ahi[arow * 72 + apos]) = (uint4){hw[0], hw[1], hw[2], hw[3]};
        *reinterpret_cast<uint4*>(&Ahi[arow * 72 + apos + 8]) = (uint4){hw[4], hw[5], hw[6], hw[7]};
        *reinterpret_cast<uint4*>(&Alo[arow * 72 + apos]) = (uint4){lw[0], lw[1], lw[2], lw[3]};
        *reinterpret_cast<uint4*>(&Alo[arow * 72 + apos + 8]) = (uint4){lw[4], lw[5], lw[6], lw[7]};
        // --- stage B: 2 planes x 192 rows x 8 chunks = 3072 chunks, 12/thread ---
        #pragma unroll
        for (int t = 0; t < 12; ++t) {
            int c = tid + 256 * t;                 // c&63 == lane
            int plane = (c >= 1536);
            int cp = c - 1536 * plane;
            int crow = cp >> 3;
            int ccol = ((cp & 3) ^ (crow & 3)) | (cp & 4);
            const unsigned short* src = (plane ? WTlo : WThi)
                + (size_t)crow * 1024 + k0 + ccol * 8;
            gload_lds16(src, &Bs2[(size_t)(c & ~63) * 8]);
        }
        __syncthreads();

        #pragma unroll
        for (int kh = 0; kh < 2; ++kh) {
            bf16x8 bh[3], bl[3];
            #pragma unroll
            for (int j = 0; j < 3; ++j) {
                int ro = (wave * 48 + j * 16 + r) * 64 + (kh * 4 + kx) * 8;
                bh[j] = *reinterpret_cast<const bf16x8*>(&Bs2[ro]);
                bl[j] = *reinterpret_cast<const bf16x8*>(&Bs2[192 * 64 + ro]);
            }
            #pragma unroll
            for (int i = 0; i < 4; ++i) {
                int ro = (i * 16 + r) * 72 + (kh * 4 + kq) * 8;
                bf16x8 ah = *reinterpret_cast<const bf16x8*>(&Ahi[ro]);
                bf16x8 al = *reinterpret_cast<const bf16x8*>(&Alo[ro]);
                #pragma unroll
                for (int j = 0; j < 3; ++j) {
                    acc[i][j] = __builtin_amdgcn_mfma_f32_16x16x32_bf16(ah, bh[j], acc[i][j], 0, 0, 0);
                    acc[i][j] = __builtin_amdgcn_mfma_f32_16x16x32_bf16(ah, bl[j], acc[i][j], 0, 0, 0);
                    acc[i][j] = __builtin_amdgcn_mfma_f32_16x16x32_bf16(al, bh[j], acc[i][j], 0, 0, 0);
                }
            }
        }
        __syncthreads();
    }

    float* P = part + (size_t)sk * 8192 * 192;
    #pragma unroll
    for (int i = 0; i < 4; ++i) {
        int row0 = bm + i * 16 + kq * 4;
        #pragma unroll
        for (int j = 0; j < 3; ++j) {
            int col = wave * 48 + j * 16 + r;
            #pragma unroll
            for (int rr = 0; rr < 4; ++rr)
                P[(size_t)(row0 + rr) * 192 + col] = acc[i][j][rr];
        }
    }
}

// ---- value projection GEMM: Vproj = Vbf @ WvT^T + b_value (bf16 out) ----
// BM=128, BN=64, BK=64 (24 KB LDS, 3 blocks/CU), 544 blocks XCD-chunked, chunk-XOR swizzle.
__global__ __launch_bounds__(256, 3) void vproj_mfma(
    const unsigned short* __restrict__ Vbf,
    const unsigned short* __restrict__ WvT,
    const float* __restrict__ bias,
    unsigned short* __restrict__ Vproj) {
    __shared__ unsigned short As[128 * 64];   // 16 KB
    __shared__ unsigned short Bs[64 * 64];    // 8 KB
    const int tid = threadIdx.x;
    const int lane = tid & 63, wave = tid >> 6;
    const int i0 = blockIdx.x;                     // 0..543
    const int s = (i0 & 7) * 68 + (i0 >> 3);       // bijective (544 = 8*68)
    const int pa = s >> 4;
    const int by = s & 15;
    const int bz = (pa >= 17) ? 1 : 0;
    const int bx = pa - 17 * bz;
    const int bm = 1920 + bz * 4096 + bx * 128;
    const int bn = by * 64;
    const int r = lane & 15, kq = lane >> 4;
    const int kx = kq ^ (r & 3);

    f32x4 acc[2][4];
    #pragma unroll
    for (int i = 0; i < 2; ++i)
        #pragma unroll
        for (int j = 0; j < 4; ++j) acc[i][j] = (f32x4){0.f, 0.f, 0.f, 0.f};

    for (int k0 = 0; k0 < 1024; k0 += 64) {
        #pragma unroll
        for (int t = 0; t < 4; ++t) {   // A: 1024 chunks
            int c = tid + 256 * t;
            int crow = c >> 3;
            int ccol = ((c & 3) ^ (crow & 3)) | (c & 4);
            gload_lds16(Vbf + (size_t)(bm + crow) * 1024 + k0 + ccol * 8,
                        &As[(size_t)(c & ~63) * 8]);
        }
        #pragma unroll
        for (int t = 0; t < 2; ++t) {   // B: 512 chunks
            int c = tid + 256 * t;
            int crow = c >> 3;
            int ccol = ((c & 3) ^ (crow & 3)) | (c & 4);
            gload_lds16(WvT + (size_t)(bn + crow) * 1024 + k0 + ccol * 8,
                        &Bs[(size_t)(c & ~63) * 8]);
        }
        __syncthreads();

        #pragma unroll
        for (int kh = 0; kh < 2; ++kh) {
            bf16x8 af[2], bfr[4];
            #pragma unroll
            for (int i = 0; i < 2; ++i)
                af[i] = *reinterpret_cast<const bf16x8*>(
                    &As[(wave * 32 + i * 16 + r) * 64 + (kh * 4 + kx) * 8]);
            #pragma unroll
            for (int j = 0; j < 4; ++j)
                bfr[j] = *reinterpret_cast<const bf16x8*>(
                    &Bs[(j * 16 + r) * 64 + (kh * 4 + kx) * 8]);
            #pragma unroll
            for (int i = 0; i < 2; ++i)
                #pragma unroll
                for (int j = 0; j < 4; ++j)
                    acc[i][j] = __builtin_amdgcn_mfma_f32_16x16x32_bf16(af[i], bfr[j], acc[i][j], 0, 0, 0);
        }
        __syncthreads();
    }

    #pragma unroll
    for (int i = 0; i < 2; ++i) {
        int row0 = bm + wave * 32 + i * 16 + kq * 4;
        #pragma unroll
        for (int j = 0; j < 4; ++j) {
            int col = bn + j * 16 + r;
            float bs = bias[col];
            #pragma unroll
            for (int rr = 0; rr < 4; ++rr)
                Vproj[(size_t)(row0 + rr) * 1024 + col] = f2bf(acc[i][j][rr] + bs);
        }
    }
}

// ------- fused: partial-sum + bias + softmax + coefficients + gather (2 rows/block) -------
__global__ __launch_bounds__(256) void sample_coef(
    const float* __restrict__ part, const float* __restrict__ b_off,
    const float* __restrict__ b_attw, const unsigned short* __restrict__ vproj,
    unsigned short* __restrict__ s_out) {
    const int n0 = blockIdx.x * 2;   // rows n0, n0+1 (same batch)
    const int tid = threadIdx.x;
    __shared__ float Ls[2][192];
    __shared__ int sIdx[2][64];
    __shared__ float sC0[2][64], sC1[2][64];
    const size_t SK = (size_t)8192 * 192;
    for (int e = tid; e < 384; e += 256) {
        int ri = (e >= 192);
        int c = e - ri * 192;
        const float* Pn = part + (size_t)(n0 + ri) * 192 + c;
        float s = (c < 128) ? b_off[c] : b_attw[c - 128];
        Ls[ri][c] = s + Pn[0] + Pn[SK] + Pn[2 * SK] + Pn[3 * SK];
    }
    __syncthreads();
    if (tid < 128) {
        int ri = tid >> 6, e = tid & 63;
        int l = (n0 + ri) & 4095;
        int h = e >> 2, p = e & 3;
        float l0 = Ls[ri][128 + h * 4 + 0], l1 = Ls[ri][128 + h * 4 + 1];
        float l2 = Ls[ri][128 + h * 4 + 2], l3 = Ls[ri][128 + h * 4 + 3];
        float mx = fmaxf(fmaxf(l0, l1), fmaxf(l2, l3));
        float e0 = expf(l0 - mx), e1 = expf(l1 - mx), e2 = expf(l2 - mx), e3 = expf(l3 - mx);
        float esum = e0 + e1 + e2 + e3;
        float aw = ((p == 0) ? e0 : (p == 1) ? e1 : (p == 2) ? e2 : e3) / esum;
        float o0 = Ls[ri][h * 8 + p * 2], o1 = Ls[ri][h * 8 + p * 2 + 1];
        float sx = fminf(fmaxf(o0, 0.f), 1.f);
        float ry = (float)l / 4095.0f;
        float sy = fminf(fmaxf(ry + o1, 0.f), 1.f);
        float ix = ((sx + 1.f) * 4096.f - 1.f) * 0.5f;
        float iy = sy * 0.5f;
        float x0f = floorf(ix);
        float fx = ix - x0f;
        int x0 = (int)x0f;
        int x1 = x0 + 1;
        float m0 = (x0 >= 0 && x0 < 4096) ? 1.f : 0.f;
        float m1 = (x1 >= 0 && x1 < 4096) ? 1.f : 0.f;
        float y0f = floorf(iy);
        float fy = iy - y0f;
        float hy = ((y0f == 0.f) ? (1.f - fy) : 0.f) + ((y0f == -1.f) ? fy : 0.f);
        sC0[ri][e] = aw * (1.f - fx) * m0 * hy;
        sC1[ri][e] = aw * fx * m1 * hy;
        sIdx[ri][e] = x0 < 0 ? 0 : (x0 > 4095 ? 4095 : x0);
    }
    __syncthreads();
    const int d = tid * 4;
    const int h = tid >> 4;
    const size_t vb = (size_t)(n0 >> 12) * 4096 * 1024;
    #pragma unroll
    for (int ri = 0; ri < 2; ++ri) {
        float a0 = 0.f, a1 = 0.f, a2 = 0.f, a3 = 0.f;
        #pragma unroll
        for (int p = 0; p < 4; ++p) {
            int e = h * 4 + p;
            int x0 = sIdx[ri][e];
            float c0 = sC0[ri][e], c1 = sC1[ri][e];
            int x1 = (x0 + 1 > 4095) ? 4095 : x0 + 1;
            ushort4 v0 = *reinterpret_cast<const ushort4*>(vproj + vb + (size_t)x0 * 1024 + d);
            ushort4 v1 = *reinterpret_cast<const ushort4*>(vproj + vb + (size_t)x1 * 1024 + d);
            a0 += c0 * bf2f(v0.x) + c1 * bf2f(v1.x);
            a1 += c0 * bf2f(v0.y) + c1 * bf2f(v1.y);
            a2 += c0 * bf2f(v0.z) + c1 * bf2f(v1.z);
            a3 += c0 * bf2f(v0.w) + c1 * bf2f(v1.w);
        }
        ushort4 o;
        o.x = f2bf(a0); o.y = f2bf(a1); o.z = f2bf(a2); o.w = f2bf(a3);
        *reinterpret_cast<ushort4*>(s_out + (size_t)(n0 + ri) * 1024 + d) = o;
    }
}

// ---- final GEMM: out = S @ WoT^T + b_out (fp32). BK=64 (32 KB LDS, 3 blocks/CU). ----
__global__ __launch_bounds__(256, 3) void gemm_bt(
    const unsigned short* __restrict__ A,   // S 8192 x 1024 bf16
    const unsigned short* __restrict__ Bt,  // WoT 1024 x 1024 bf16
    const float* __restrict__ bias,         // b_out
    float* __restrict__ C) {
    __shared__ unsigned short As[128 * 64];  // 16 KB
    __shared__ unsigned short Bs[128 * 64];  // 16 KB
    const int tid = threadIdx.x;
    const int lane = tid & 63;
    const int wave = tid >> 6;
    const int i0 = blockIdx.x;                // 0..511
    const int s = (i0 & 7) * 64 + (i0 >> 3);  // bijective (512 = 8*64)
    const int bm = (s >> 3) * 128;
    const int bn = (s & 7) * 128;
    const int wr = wave >> 1;
    const int wc = wave & 1;
    const int r = lane & 15;
    const int kq = lane >> 4;
    const int kx = kq ^ (r & 3);

    f32x4 acc[4][4];
    #pragma unroll
    for (int i = 0; i < 4; ++i)
        #pragma unroll
        for (int j = 0; j < 4; ++j) acc[i][j] = (f32x4){0.f, 0.f, 0.f, 0.f};

    for (int k0 = 0; k0 < 1024; k0 += 64) {
        const unsigned short* Ab = A + (size_t)bm * 1024 + k0;
        const unsigned short* Bb = Bt + (size_t)bn * 1024 + k0;
        #pragma unroll
        for (int t = 0; t < 4; ++t) {   // 1024 chunks per operand, 4/thread
            int c = tid + 256 * t;
            int crow = c >> 3;
            int ccol = ((c & 3) ^ (crow & 3)) | (c & 4);
            gload_lds16(Ab + (size_t)crow * 1024 + ccol * 8, &As[(size_t)(c & ~63) * 8]);
        }
        #pragma unroll
        for (int t = 0; t < 4; ++t) {
            int c = tid + 256 * t;
            int crow = c >> 3;
            int ccol = ((c & 3) ^ (crow & 3)) | (c & 4);
            gload_lds16(Bb + (size_t)crow * 1024 + ccol * 8, &Bs[(size_t)(c & ~63) * 8]);
        }
        __syncthreads();

        #pragma unroll
        for (int kh = 0; kh < 2; ++kh) {
            bf16x8 af[4], bfr[4];
            #pragma unroll
            for (int i = 0; i < 4; ++i)
                af[i] = *reinterpret_cast<const bf16x8*>(
                    &As[(wr * 64 + i * 16 + r) * 64 + (kh * 4 + kx) * 8]);
            #pragma unroll
            for (int j = 0; j < 4; ++j)
                bfr[j] = *reinterpret_cast<const bf16x8*>(
                    &Bs[(wc * 64 + j * 16 + r) * 64 + (kh * 4 + kx) * 8]);
            #pragma unroll
            for (int i = 0; i < 4; ++i)
                #pragma unroll
                for (int j = 0; j < 4; ++j)
                    acc[i][j] = __builtin_amdgcn_mfma_f32_16x16x32_bf16(af[i], bfr[j], acc[i][j], 0, 0, 0);
        }
        __syncthreads();
    }

    #pragma unroll
    for (int i = 0; i < 4; ++i) {
        int row0 = bm + wr * 64 + i * 16 + kq * 4;
        #pragma unroll
        for (int j = 0; j < 4; ++j) {
            int col = bn + wc * 64 + j * 16 + r;
            float bs = bias[col];
            #pragma unroll
            for (int rr = 0; rr < 4; ++rr)
                C[(size_t)(row0 + rr) * 1024 + col] = acc[i][j][rr] + bs;
        }
    }
}

extern "C" void kernel_launch(void* const* d_in, const int* in_sizes, int n_in,
                              void* d_out, int out_size, void* d_ws, size_t ws_size,
                              hipStream_t stream) {
    const float* query  = (const float*)d_in[0];
    const float* value  = (const float*)d_in[2];
    const float* w_value = (const float*)d_in[5];
    const float* b_value = (const float*)d_in[6];
    const float* w_off   = (const float*)d_in[7];
    const float* b_off   = (const float*)d_in[8];
    const float* w_attw  = (const float*)d_in[9];
    const float* b_attw  = (const float*)d_in[10];
    const float* w_out   = (const float*)d_in[11];
    const float* b_out   = (const float*)d_in[12];
    float* out = (float*)d_out;

    char* w = (char*)d_ws;
    unsigned short* Vbf   = (unsigned short*)(w);                       // 0..16
    unsigned short* WvT   = (unsigned short*)(w + (16ull << 20));       // 16..18
    unsigned short* WoT   = (unsigned short*)(w + (18ull << 20));       // 18..20
    unsigned short* Vproj = (unsigned short*)(w + (20ull << 20));       // 20..36
    unsigned short* S     = (unsigned short*)(w + (36ull << 20));       // 36..52
    unsigned short* WThi  = (unsigned short*)(w + (53ull << 20));       // 53..53.4
    unsigned short* WTlo  = (unsigned short*)(w + (54ull << 20));       // 54..54.4
    float*          Part  = (float*)(w + (56ull << 20));                // 56..81.2
    // all regions disjoint; no lifetime aliasing.

    // 1. fused prep: weight transposes/splits + value->bf16 slice
    prep_all<<<6592, 256, 0, stream>>>(w_value, w_out, w_off, w_attw, value,
                                       WvT, WoT, WThi, WTlo, Vbf);
    // 2. off/attw logits via split-bf16 MFMA (split-K=4 partials), BK=64
    offw_mfma<<<dim3(128, 4), 256, 0, stream>>>(query, WThi, WTlo, Part);
    // 3. v = Vbf @ w_value + b_value (bf16 out), BK=64, XCD-swz, 3 blocks/CU
    vproj_mfma<<<544, 256, 0, stream>>>(Vbf, WvT, b_value, Vproj);
    // 4. partial-sum + bias + softmax + coefficients + gather -> s (bf16), 2 rows/block
    sample_coef<<<4096, 256, 0, stream>>>(Part, b_off, b_attw, Vproj, S);
    // 5. out = s @ w_out + b_out (fp32 out), BK=64, XCD-swz, 3 blocks/CU
    gemm_bt<<<512, 256, 0, stream>>>(S, WoT, b_out, out);
}